// Round 1
// baseline (769.215 us; speedup 1.0000x reference)
//
#include <hip/hip_runtime.h>

#define D 48
#define W 3
#define NX 160
#define NY 160
#define NZ 160
#define NPTS (NX*NY*NZ)        // 4,096,000
#define KNBR 8
#define EPSV 1e-5f
#define NTV (159*159*159)      // 4,019,679

// workspace layout (float offsets)
#define T1_OFF 0
#define T1_SZ (W*NX*D*D)             // 1,105,920
#define T2_OFF (T1_OFF + T1_SZ)
#define T2_SZ (W*NX*NY*D)            // 3,686,400
#define G3_OFF (T2_OFF + T2_SZ)      // g3[point*3 + w], 12,288,000 floats

// ---------------------------------------------------------------------------
// k1: t1[w][a][q][r] = sum_p x[a][p] * wt[w][p][q][r]
// grid (12, 10, 3), block 256 (4 waves; wave -> q, lane -> r)
__global__ __launch_bounds__(256) void k1(const float* __restrict__ x,
                                          const float* __restrict__ wt,
                                          float* __restrict__ t1) {
    int lane = threadIdx.x & 63;
    int wv   = threadIdx.x >> 6;
    int q    = blockIdx.x * 4 + wv;
    int a0   = blockIdx.y * 16;
    int w    = blockIdx.z;
    bool act = lane < D;

    float wreg[D];
#pragma unroll
    for (int p = 0; p < D; ++p)
        wreg[p] = act ? wt[((w*D + p)*D + q)*D + lane] : 0.f;

    for (int ai = 0; ai < 16; ++ai) {
        int a = a0 + ai;
        const float4* xp = (const float4*)(x + a*D);
        float s = 0.f;
#pragma unroll
        for (int j = 0; j < D/4; ++j) {
            float4 xv = xp[j];
            s += xv.x * wreg[4*j+0];
            s += xv.y * wreg[4*j+1];
            s += xv.z * wreg[4*j+2];
            s += xv.w * wreg[4*j+3];
        }
        if (act) t1[((w*NX + a)*D + q)*D + lane] = s;
    }
}

// ---------------------------------------------------------------------------
// k2: t2[w][a][b][r] = sum_q y[b][q] * t1[w][a][q][r]
// grid (160, 3) = (a, w), block 256 (wave -> 40 b's, lane -> r)
__global__ __launch_bounds__(256) void k2(const float* __restrict__ y,
                                          const float* __restrict__ t1,
                                          float* __restrict__ t2) {
    int lane = threadIdx.x & 63;
    int wv   = threadIdx.x >> 6;
    int a    = blockIdx.x;
    int w    = blockIdx.y;
    bool act = lane < D;

    float t1reg[D];
    const float* t1p = t1 + ((w*NX + a)*D)*D;
#pragma unroll
    for (int q = 0; q < D; ++q)
        t1reg[q] = act ? t1p[q*D + lane] : 0.f;

    for (int bi = 0; bi < 40; ++bi) {
        int b = wv*40 + bi;
        const float4* yp = (const float4*)(y + b*D);
        float s = 0.f;
#pragma unroll
        for (int j = 0; j < D/4; ++j) {
            float4 yv = yp[j];
            s += yv.x * t1reg[4*j+0];
            s += yv.y * t1reg[4*j+1];
            s += yv.z * t1reg[4*j+2];
            s += yv.w * t1reg[4*j+3];
        }
        if (act) t2[((w*NX + a)*NY + b)*D + lane] = s;
    }
}

// ---------------------------------------------------------------------------
// k3: g3[((a*NY+b)*NZ + c)*3 + w] = sum_r z[c][r] * t2[w][a][b][r]
// grid (800), block 192 (lane c in [0,192), active c<160); 32 pairs per block
#define PPB 32
__global__ __launch_bounds__(192) void k3(const float* __restrict__ z,
                                          const float* __restrict__ t2,
                                          float* __restrict__ g3) {
    int c = threadIdx.x;
    bool act = c < NZ;

    float zreg[D];
#pragma unroll
    for (int r = 0; r < D; ++r)
        zreg[r] = act ? z[c*D + r] : 0.f;

    int p0 = blockIdx.x * PPB;
    for (int i = 0; i < PPB; ++i) {
        int pair = p0 + i;
        int a = pair / NY, b = pair - a*NY;
        float acc[W];
#pragma unroll
        for (int w = 0; w < W; ++w) {
            const float4* t2p = (const float4*)(t2 + ((w*NX + a)*NY + b)*D);
            float s = 0.f;
#pragma unroll
            for (int j = 0; j < D/4; ++j) {
                float4 tv4 = t2p[j];
                s += tv4.x * zreg[4*j+0];
                s += tv4.y * zreg[4*j+1];
                s += tv4.z * zreg[4*j+2];
                s += tv4.w * zreg[4*j+3];
            }
            acc[w] = s;
        }
        if (act) {
            float* o = g3 + (size_t)((a*NY + b)*NZ + c) * 3;
            o[0] = acc[0]; o[1] = acc[1]; o[2] = acc[2];
        }
    }
}

// ---------------------------------------------------------------------------
// TV: mean over (159^3) of sum_w sqrt(eps + dc^2 + db^2 + da^2)
__global__ __launch_bounds__(256) void ktv(const float* __restrict__ g3,
                                           float* __restrict__ outreg) {
    int t = blockIdx.x * 256 + threadIdx.x;
    float v = 0.f;
    if (t < NTV) {
        int a   = t / (159*159);
        int rem = t - a*(159*159);
        int b   = rem / 159;
        int c   = rem - b*159;
        const float* p = g3 + (size_t)((a*NY + b)*NZ + c) * 3;
#pragma unroll
        for (int w = 0; w < W; ++w) {
            float g0 = p[w];
            float dc = p[3       + w] - g0;
            float db = p[3*NZ    + w] - g0;
            float da = p[3*NY*NZ + w] - g0;
            v += sqrtf(EPSV + dc*dc + db*db + da*da);
        }
    }
#pragma unroll
    for (int off = 32; off > 0; off >>= 1)
        v += __shfl_down(v, off, 64);
    __shared__ float sred[4];
    int lane = threadIdx.x & 63, wv = threadIdx.x >> 6;
    if (lane == 0) sred[wv] = v;
    __syncthreads();
    if (threadIdx.x == 0) {
        float s = (sred[0] + sred[1] + sred[2] + sred[3]) * (1.0f / (float)NTV);
        atomicAdd(outreg, s);
    }
}

// ---------------------------------------------------------------------------
// gather: out[n*3+w] = sum_k g3[idx[n][k]*3 + w] * bw[n][k]
__global__ __launch_bounds__(256) void kgather(const int* __restrict__ bidx,
                                               const float* __restrict__ bw,
                                               const float* __restrict__ g3,
                                               float* __restrict__ out,
                                               int np) {
    int n = blockIdx.x * 256 + threadIdx.x;
    if (n >= np) return;
    const int4*   ip = (const int4*)(bidx) + (size_t)n*2;
    const float4* wp = (const float4*)(bw) + (size_t)n*2;
    int4   i0 = ip[0], i1 = ip[1];
    float4 w0 = wp[0], w1 = wp[1];
    int   ids[KNBR] = {i0.x, i0.y, i0.z, i0.w, i1.x, i1.y, i1.z, i1.w};
    float wws[KNBR] = {w0.x, w0.y, w0.z, w0.w, w1.x, w1.y, w1.z, w1.w};
    float a0 = 0.f, a1 = 0.f, a2 = 0.f;
#pragma unroll
    for (int k = 0; k < KNBR; ++k) {
        const float* gp = g3 + (size_t)ids[k] * 3;
        float wk = wws[k];
        a0 += gp[0] * wk;
        a1 += gp[1] * wk;
        a2 += gp[2] * wk;
    }
    float* op = out + (size_t)n * 3;
    op[0] = a0; op[1] = a1; op[2] = a2;
}

// ---------------------------------------------------------------------------
extern "C" void kernel_launch(void* const* d_in, const int* in_sizes, int n_in,
                              void* d_out, int out_size, void* d_ws, size_t ws_size,
                              hipStream_t stream) {
    const float* x    = (const float*)d_in[0];
    const float* y    = (const float*)d_in[1];
    const float* z    = (const float*)d_in[2];
    const float* wt   = (const float*)d_in[3];
    const int*   bidx = (const int*)d_in[4];
    const float* bw   = (const float*)d_in[5];
    float* out = (float*)d_out;
    float* ws  = (float*)d_ws;

    float* t1 = ws + T1_OFF;
    float* t2 = ws + T2_OFF;
    float* g3 = ws + G3_OFF;
    int np = in_sizes[4] / KNBR;   // 2,000,000

    k1<<<dim3(12, 10, 3), 256, 0, stream>>>(x, wt, t1);
    k2<<<dim3(160, 3),    256, 0, stream>>>(y, t1, t2);
    k3<<<dim3(800),       192, 0, stream>>>(z, t2, g3);

    // zero the scalar slot (harness poisons d_out), then reduce into it
    hipMemsetAsync((char*)d_out + (size_t)(out_size - 1) * 4, 0, 4, stream);
    ktv<<<dim3((NTV + 255) / 256), 256, 0, stream>>>(g3, out + (out_size - 1));

    kgather<<<dim3((np + 255) / 256), 256, 0, stream>>>(bidx, bw, g3, out, np);
}

// Round 2
// 544.972 us; speedup vs baseline: 1.4115x; 1.4115x over previous
//
#include <hip/hip_runtime.h>
#include <hip/hip_fp16.h>

#define D 48
#define W 3
#define NX 160
#define NY 160
#define NZ 160
#define NPTS (NX*NY*NZ)        // 4,096,000
#define KNBR 8
#define EPSV 1e-5f
#define NTV (159*159*159)      // 4,019,679
#define NBTV 2048              // TV partial blocks

// workspace layout (float offsets)
#define T1_OFF 0
#define T1_SZ (W*NX*D*D)              // 1,105,920
#define T2_OFF (T1_OFF + T1_SZ)
#define T2_SZ (W*NX*NY*D)             // 3,686,400
#define TVP_OFF (T2_OFF + T2_SZ)      // 2048 floats of TV partials
#define G3_OFF (TVP_OFF + NBTV)       // byte offset 4B*(4,794,368) — 16B aligned
// g3h: NPTS entries of 8 bytes (half4: g0,g1,g2,pad), accessed as uint2

__device__ inline void unpack3(uint2 u, float& f0, float& f1, float& f2) {
    __half2 lo = *reinterpret_cast<__half2*>(&u.x);
    __half2 hi = *reinterpret_cast<__half2*>(&u.y);
    f0 = __low2float(lo);
    f1 = __high2float(lo);
    f2 = __low2float(hi);
}

// ---------------------------------------------------------------------------
// k1: t1[w][a][q][r] = sum_p x[a][p] * wt[w][p][q][r]
__global__ __launch_bounds__(256) void k1(const float* __restrict__ x,
                                          const float* __restrict__ wt,
                                          float* __restrict__ t1) {
    int lane = threadIdx.x & 63;
    int wv   = threadIdx.x >> 6;
    int q    = blockIdx.x * 4 + wv;
    int a0   = blockIdx.y * 16;
    int w    = blockIdx.z;
    bool act = lane < D;

    float wreg[D];
#pragma unroll
    for (int p = 0; p < D; ++p)
        wreg[p] = act ? wt[((w*D + p)*D + q)*D + lane] : 0.f;

    for (int ai = 0; ai < 16; ++ai) {
        int a = a0 + ai;
        const float4* xp = (const float4*)(x + a*D);
        float s = 0.f;
#pragma unroll
        for (int j = 0; j < D/4; ++j) {
            float4 xv = xp[j];
            s += xv.x * wreg[4*j+0];
            s += xv.y * wreg[4*j+1];
            s += xv.z * wreg[4*j+2];
            s += xv.w * wreg[4*j+3];
        }
        if (act) t1[((w*NX + a)*D + q)*D + lane] = s;
    }
}

// ---------------------------------------------------------------------------
// k2: t2[w][a][b][r] = sum_q y[b][q] * t1[w][a][q][r]
__global__ __launch_bounds__(256) void k2(const float* __restrict__ y,
                                          const float* __restrict__ t1,
                                          float* __restrict__ t2) {
    int lane = threadIdx.x & 63;
    int wv   = threadIdx.x >> 6;
    int a    = blockIdx.x;
    int w    = blockIdx.y;
    bool act = lane < D;

    float t1reg[D];
    const float* t1p = t1 + ((w*NX + a)*D)*D;
#pragma unroll
    for (int q = 0; q < D; ++q)
        t1reg[q] = act ? t1p[q*D + lane] : 0.f;

    for (int bi = 0; bi < 40; ++bi) {
        int b = wv*40 + bi;
        const float4* yp = (const float4*)(y + b*D);
        float s = 0.f;
#pragma unroll
        for (int j = 0; j < D/4; ++j) {
            float4 yv = yp[j];
            s += yv.x * t1reg[4*j+0];
            s += yv.y * t1reg[4*j+1];
            s += yv.z * t1reg[4*j+2];
            s += yv.w * t1reg[4*j+3];
        }
        if (act) t2[((w*NX + a)*NY + b)*D + lane] = s;
    }
}

// ---------------------------------------------------------------------------
// k3: g3h[(a*NY+b)*NZ + c] = half4{ sum_r z[c][r]*t2[w][a][b][r] for w in 0..2 }
#define PPB 8
__global__ __launch_bounds__(192) void k3(const float* __restrict__ z,
                                          const float* __restrict__ t2,
                                          uint2* __restrict__ g3h) {
    int c = threadIdx.x;
    bool act = c < NZ;

    float zreg[D];
#pragma unroll
    for (int r = 0; r < D; ++r)
        zreg[r] = act ? z[c*D + r] : 0.f;

    int p0 = blockIdx.x * PPB;
    for (int i = 0; i < PPB; ++i) {
        int pair = p0 + i;
        int a = pair / NY, b = pair - a*NY;
        float acc[W];
#pragma unroll
        for (int w = 0; w < W; ++w) {
            const float4* t2p = (const float4*)(t2 + ((w*NX + a)*NY + b)*D);
            float s = 0.f;
#pragma unroll
            for (int j = 0; j < D/4; ++j) {
                float4 tv4 = t2p[j];
                s += tv4.x * zreg[4*j+0];
                s += tv4.y * zreg[4*j+1];
                s += tv4.z * zreg[4*j+2];
                s += tv4.w * zreg[4*j+3];
            }
            acc[w] = s;
        }
        if (act) {
            __half2 lo = __halves2half2(__float2half_rn(acc[0]), __float2half_rn(acc[1]));
            __half2 hi = __halves2half2(__float2half_rn(acc[2]), __float2half_rn(0.f));
            uint2 u;
            u.x = *reinterpret_cast<unsigned*>(&lo);
            u.y = *reinterpret_cast<unsigned*>(&hi);
            g3h[(size_t)((a*NY + b)*NZ + c)] = u;
        }
    }
}

// ---------------------------------------------------------------------------
// TV: per-block partial sums (no contended atomics). partial[b] for b<NBTV.
__global__ __launch_bounds__(256) void ktv(const uint2* __restrict__ g3h,
                                           float* __restrict__ partial) {
    float v = 0.f;
    for (int t = blockIdx.x * 256 + threadIdx.x; t < NTV; t += NBTV * 256) {
        int a   = t / (159*159);
        int rem = t - a*(159*159);
        int b   = rem / 159;
        int c   = rem - b*159;
        int point = (a*NY + b)*NZ + c;
        uint2 u0 = g3h[point];
        uint2 uc = g3h[point + 1];
        uint2 ub = g3h[point + NZ];
        uint2 ua = g3h[point + NY*NZ];
        float b0,b1,b2, c0,c1,c2, d0,d1,d2, e0,e1,e2;
        unpack3(u0, b0,b1,b2);
        unpack3(uc, c0,c1,c2);
        unpack3(ub, d0,d1,d2);
        unpack3(ua, e0,e1,e2);
        float x0 = c0-b0, y0 = d0-b0, z0 = e0-b0;
        float x1 = c1-b1, y1 = d1-b1, z1 = e1-b1;
        float x2 = c2-b2, y2 = d2-b2, z2 = e2-b2;
        v += sqrtf(EPSV + x0*x0 + y0*y0 + z0*z0);
        v += sqrtf(EPSV + x1*x1 + y1*y1 + z1*z1);
        v += sqrtf(EPSV + x2*x2 + y2*y2 + z2*z2);
    }
#pragma unroll
    for (int off = 32; off > 0; off >>= 1)
        v += __shfl_down(v, off, 64);
    __shared__ float sred[4];
    int lane = threadIdx.x & 63, wv = threadIdx.x >> 6;
    if (lane == 0) sred[wv] = v;
    __syncthreads();
    if (threadIdx.x == 0)
        partial[blockIdx.x] = sred[0] + sred[1] + sred[2] + sred[3];
}

// final reduce of NBTV partials -> scalar (mean)
__global__ __launch_bounds__(256) void kred(const float* __restrict__ partial,
                                            float* __restrict__ outreg) {
    float v = 0.f;
    for (int i = threadIdx.x; i < NBTV; i += 256) v += partial[i];
#pragma unroll
    for (int off = 32; off > 0; off >>= 1)
        v += __shfl_down(v, off, 64);
    __shared__ float sred[4];
    int lane = threadIdx.x & 63, wv = threadIdx.x >> 6;
    if (lane == 0) sred[wv] = v;
    __syncthreads();
    if (threadIdx.x == 0)
        outreg[0] = (sred[0] + sred[1] + sred[2] + sred[3]) * (1.0f / (float)NTV);
}

// ---------------------------------------------------------------------------
// gather: out[n*3+w] = sum_k g3h[idx[n][k]].w * bw[n][k]
__global__ __launch_bounds__(256) void kgather(const int* __restrict__ bidx,
                                               const float* __restrict__ bw,
                                               const uint2* __restrict__ g3h,
                                               float* __restrict__ out,
                                               int np) {
    int n = blockIdx.x * 256 + threadIdx.x;
    if (n >= np) return;
    const int4*   ip = (const int4*)(bidx) + (size_t)n*2;
    const float4* wp = (const float4*)(bw) + (size_t)n*2;
    int4   i0 = ip[0], i1 = ip[1];
    float4 w0 = wp[0], w1 = wp[1];
    int   ids[KNBR] = {i0.x, i0.y, i0.z, i0.w, i1.x, i1.y, i1.z, i1.w};
    float wws[KNBR] = {w0.x, w0.y, w0.z, w0.w, w1.x, w1.y, w1.z, w1.w};
    float a0 = 0.f, a1 = 0.f, a2 = 0.f;
#pragma unroll
    for (int k = 0; k < KNBR; ++k) {
        uint2 u = g3h[(size_t)ids[k]];
        float f0, f1, f2;
        unpack3(u, f0, f1, f2);
        float wk = wws[k];
        a0 += f0 * wk;
        a1 += f1 * wk;
        a2 += f2 * wk;
    }
    float* op = out + (size_t)n * 3;
    op[0] = a0; op[1] = a1; op[2] = a2;
}

// ---------------------------------------------------------------------------
extern "C" void kernel_launch(void* const* d_in, const int* in_sizes, int n_in,
                              void* d_out, int out_size, void* d_ws, size_t ws_size,
                              hipStream_t stream) {
    const float* x    = (const float*)d_in[0];
    const float* y    = (const float*)d_in[1];
    const float* z    = (const float*)d_in[2];
    const float* wt   = (const float*)d_in[3];
    const int*   bidx = (const int*)d_in[4];
    const float* bw   = (const float*)d_in[5];
    float* out = (float*)d_out;
    float* ws  = (float*)d_ws;

    float* t1  = ws + T1_OFF;
    float* t2  = ws + T2_OFF;
    float* tvp = ws + TVP_OFF;
    uint2* g3h = (uint2*)(ws + G3_OFF);
    int np = in_sizes[4] / KNBR;   // 2,000,000

    k1<<<dim3(12, 10, 3), 256, 0, stream>>>(x, wt, t1);
    k2<<<dim3(160, 3),    256, 0, stream>>>(y, t1, t2);
    k3<<<dim3(NX*NY/PPB), 192, 0, stream>>>(z, t2, g3h);

    ktv <<<dim3(NBTV), 256, 0, stream>>>(g3h, tvp);
    kred<<<dim3(1),    256, 0, stream>>>(tvp, out + (out_size - 1));

    kgather<<<dim3((np + 255) / 256), 256, 0, stream>>>(bidx, bw, g3h, out, np);
}

// Round 4
// 524.255 us; speedup vs baseline: 1.4673x; 1.0395x over previous
//
#include <hip/hip_runtime.h>
#include <hip/hip_fp16.h>

#define D 48
#define W 3
#define NX 160
#define NY 160
#define NZ 160
#define NPTS (NX*NY*NZ)        // 4,096,000
#define KNBR 8
#define EPSV 1e-5f
#define NTV (159*159*159)      // 4,019,679
#define NBTV 2048              // TV partial blocks
#define TVROWS (159*159)
#define CPAIRS 80
#define TVSLOTS (TVROWS*CPAIRS)   // 2,022,480

typedef int   vint4   __attribute__((ext_vector_type(4)));
typedef float vfloat4 __attribute__((ext_vector_type(4)));

// workspace layout (float offsets)
#define T1_OFF 0
#define T1_SZ (W*NX*D*D)              // 1,105,920 floats
#define TVP_OFF (T1_OFF + T1_SZ)
#define G3_OFF (TVP_OFF + NBTV)       // 1,107,968 floats -> byte 4,431,872 (16B aligned)
// g3h: NPTS entries of 8 bytes (half4: g0,g1,g2,pad) as uint2

__device__ inline void unpack3(uint2 u, float& f0, float& f1, float& f2) {
    __half2 lo = *reinterpret_cast<__half2*>(&u.x);
    __half2 hi = *reinterpret_cast<__half2*>(&u.y);
    f0 = __low2float(lo);
    f1 = __high2float(lo);
    f2 = __low2float(hi);
}

// ---------------------------------------------------------------------------
// k1: t1[w][a][q][r] = sum_p x[a][p] * wt[w][p][q][r]
__global__ __launch_bounds__(256) void k1(const float* __restrict__ x,
                                          const float* __restrict__ wt,
                                          float* __restrict__ t1) {
    int lane = threadIdx.x & 63;
    int wv   = threadIdx.x >> 6;
    int q    = blockIdx.x * 4 + wv;
    int a0   = blockIdx.y * 16;
    int w    = blockIdx.z;
    bool act = lane < D;

    float wreg[D];
#pragma unroll
    for (int p = 0; p < D; ++p)
        wreg[p] = act ? wt[((w*D + p)*D + q)*D + lane] : 0.f;

    for (int ai = 0; ai < 16; ++ai) {
        int a = a0 + ai;
        const float4* xp = (const float4*)(x + a*D);
        float s = 0.f;
#pragma unroll
        for (int j = 0; j < D/4; ++j) {
            float4 xv = xp[j];
            s += xv.x * wreg[4*j+0];
            s += xv.y * wreg[4*j+1];
            s += xv.z * wreg[4*j+2];
            s += xv.w * wreg[4*j+3];
        }
        if (act) t1[((w*NX + a)*D + q)*D + lane] = s;
    }
}

// ---------------------------------------------------------------------------
// kbcd: fused k2+k3 for one (a, b-half). t1 slice -> LDS, t2 -> LDS, pack g3h.
#define BH 80
__global__ __launch_bounds__(192) void kbcd(const float* __restrict__ y,
                                            const float* __restrict__ z,
                                            const float* __restrict__ t1,
                                            uint2* __restrict__ g3h) {
    __shared__ float t1s[W*D*D];     // [w][q][r], 27.6 KB
    __shared__ float t2s[W*BH*D];    // [w][bh][r], 46.1 KB
    int tid = threadIdx.x;
    int a   = blockIdx.y;
    int b0  = blockIdx.x * BH;

    // stage D prefetch: z row into registers (lane c = tid, act c<160)
    int c = tid;
    bool act = c < NZ;
    float zreg[D];
#pragma unroll
    for (int j = 0; j < D/4; ++j) {
        float4 zv = act ? ((const float4*)(z + c*D))[j] : make_float4(0,0,0,0);
        zreg[4*j+0] = zv.x; zreg[4*j+1] = zv.y; zreg[4*j+2] = zv.z; zreg[4*j+3] = zv.w;
    }

    // stage B: load t1 slice for this a (coalesced; same flat layout)
    for (int i = tid; i < W*D*D; i += 192) {
        int w = i / (D*D), rem = i - w*(D*D);
        t1s[i] = t1[(size_t)(w*NX + a)*(D*D) + rem];
    }
    __syncthreads();

    // stage C: t2s[w][bh][r] = sum_q y[b0+bh][q] * t1s[w][q][r]; float4 outputs
    for (int i = tid; i < W*BH*(D/4); i += 192) {
        int w   = i / (BH*(D/4));
        int rem = i - w*(BH*(D/4));
        int bh  = rem / (D/4);
        int r4  = rem - bh*(D/4);
        const float4* yb  = (const float4*)(y + (b0 + bh)*D);
        const float4* t1v = (const float4*)(t1s + w*D*D) + r4;
        float4 s = make_float4(0,0,0,0);
#pragma unroll
        for (int q4 = 0; q4 < D/4; ++q4) {
            float4 yv = yb[q4];
#pragma unroll
            for (int u = 0; u < 4; ++u) {
                float yq = (u==0) ? yv.x : (u==1) ? yv.y : (u==2) ? yv.z : yv.w;
                float4 tv = t1v[(q4*4+u)*(D/4)];
                s.x += yq*tv.x; s.y += yq*tv.y; s.z += yq*tv.z; s.w += yq*tv.w;
            }
        }
        ((float4*)t2s)[i] = s;
    }
    __syncthreads();

    // stage D: g3h[(a*NY+b)*NZ+c] = half4{ t2s[w][bh][:] . zreg }
    for (int bh = 0; bh < BH; ++bh) {
        float acc[W];
#pragma unroll
        for (int w = 0; w < W; ++w) {
            const float4* t2v = (const float4*)(t2s + (w*BH + bh)*D);
            float s = 0.f;
#pragma unroll
            for (int j = 0; j < D/4; ++j) {
                float4 t = t2v[j];
                s += t.x*zreg[4*j+0] + t.y*zreg[4*j+1] + t.z*zreg[4*j+2] + t.w*zreg[4*j+3];
            }
            acc[w] = s;
        }
        if (act) {
            __half2 lo = __halves2half2(__float2half_rn(acc[0]), __float2half_rn(acc[1]));
            __half2 hi = __halves2half2(__float2half_rn(acc[2]), __float2half_rn(0.f));
            uint2 u;
            u.x = *reinterpret_cast<unsigned*>(&lo);
            u.y = *reinterpret_cast<unsigned*>(&hi);
            g3h[(size_t)((a*NY + (b0+bh))*NZ + c)] = u;
        }
    }
}

// ---------------------------------------------------------------------------
__device__ inline float tv3(uint2 u0, uint2 uc, uint2 ub, uint2 ua) {
    float b0,b1,b2, c0,c1,c2, d0,d1,d2, e0,e1,e2;
    unpack3(u0,b0,b1,b2); unpack3(uc,c0,c1,c2);
    unpack3(ub,d0,d1,d2); unpack3(ua,e0,e1,e2);
    float x0=c0-b0, y0=d0-b0, z0=e0-b0;
    float x1=c1-b1, y1=d1-b1, z1=e1-b1;
    float x2=c2-b2, y2=d2-b2, z2=e2-b2;
    return sqrtf(EPSV + x0*x0 + y0*y0 + z0*z0)
         + sqrtf(EPSV + x1*x1 + y1*y1 + z1*z1)
         + sqrtf(EPSV + x2*x2 + y2*y2 + z2*z2);
}

// TV over c-pairs: 2 points per slot via uint4 loads (4 loads / 2 points)
__global__ __launch_bounds__(256) void ktv(const uint2* __restrict__ g3h,
                                           float* __restrict__ partial) {
    float v = 0.f;
    for (int s = blockIdx.x * 256 + threadIdx.x; s < TVSLOTS; s += NBTV * 256) {
        int c2  = s % CPAIRS;
        int row = s / CPAIRS;
        int b   = row % 159;
        int a   = row / 159;
        int c   = 2*c2;
        size_t p = (size_t)(a*NY + b)*NZ + c;
        uint4 u0 = *(const uint4*)(g3h + p);          // points c, c+1
        uint4 ub = *(const uint4*)(g3h + p + NZ);     // b+1 neighbors
        uint4 ua = *(const uint4*)(g3h + p + NY*NZ);  // a+1 neighbors
        uint2 un = g3h[p + 2];                        // c+2 (safe in-bounds)
        uint2 u0l = make_uint2(u0.x, u0.y), u0h = make_uint2(u0.z, u0.w);
        uint2 ubl = make_uint2(ub.x, ub.y), ubh = make_uint2(ub.z, ub.w);
        uint2 ual = make_uint2(ua.x, ua.y), uah = make_uint2(ua.z, ua.w);
        v += tv3(u0l, u0h, ubl, ual);
        if (c + 1 < 159)
            v += tv3(u0h, un, ubh, uah);
    }
#pragma unroll
    for (int off = 32; off > 0; off >>= 1)
        v += __shfl_down(v, off, 64);
    __shared__ float sred[4];
    int lane = threadIdx.x & 63, wv = threadIdx.x >> 6;
    if (lane == 0) sred[wv] = v;
    __syncthreads();
    if (threadIdx.x == 0)
        partial[blockIdx.x] = sred[0] + sred[1] + sred[2] + sred[3];
}

__global__ __launch_bounds__(256) void kred(const float* __restrict__ partial,
                                            float* __restrict__ outreg) {
    float v = 0.f;
    for (int i = threadIdx.x; i < NBTV; i += 256) v += partial[i];
#pragma unroll
    for (int off = 32; off > 0; off >>= 1)
        v += __shfl_down(v, off, 64);
    __shared__ float sred[4];
    int lane = threadIdx.x & 63, wv = threadIdx.x >> 6;
    if (lane == 0) sred[wv] = v;
    __syncthreads();
    if (threadIdx.x == 0)
        outreg[0] = (sred[0] + sred[1] + sred[2] + sred[3]) * (1.0f / (float)NTV);
}

// ---------------------------------------------------------------------------
// gather: 2 points per thread (n, n+np/2) for 16-deep random-load MLP.
__global__ __launch_bounds__(256) void kgather(const int* __restrict__ bidx,
                                               const float* __restrict__ bw,
                                               const uint2* __restrict__ g3h,
                                               float* __restrict__ out,
                                               int np) {
    int gid  = blockIdx.x * 256 + threadIdx.x;
    int half = np >> 1;
    if (gid >= half) return;
    int n1 = gid, n2 = gid + half;

    const vint4*   ip = (const vint4*)bidx;
    const vfloat4* wp = (const vfloat4*)bw;
    vint4   i0 = __builtin_nontemporal_load(ip + (size_t)n1*2);
    vint4   i1 = __builtin_nontemporal_load(ip + (size_t)n1*2 + 1);
    vint4   j0 = __builtin_nontemporal_load(ip + (size_t)n2*2);
    vint4   j1 = __builtin_nontemporal_load(ip + (size_t)n2*2 + 1);
    vfloat4 w0 = __builtin_nontemporal_load(wp + (size_t)n1*2);
    vfloat4 w1 = __builtin_nontemporal_load(wp + (size_t)n1*2 + 1);
    vfloat4 v0 = __builtin_nontemporal_load(wp + (size_t)n2*2);
    vfloat4 v1 = __builtin_nontemporal_load(wp + (size_t)n2*2 + 1);

    int   idsA[KNBR] = {i0.x, i0.y, i0.z, i0.w, i1.x, i1.y, i1.z, i1.w};
    int   idsB[KNBR] = {j0.x, j0.y, j0.z, j0.w, j1.x, j1.y, j1.z, j1.w};
    float wwsA[KNBR] = {w0.x, w0.y, w0.z, w0.w, w1.x, w1.y, w1.z, w1.w};
    float wwsB[KNBR] = {v0.x, v0.y, v0.z, v0.w, v1.x, v1.y, v1.z, v1.w};

    // issue all 16 random loads before consuming
    uint2 uA[KNBR], uB[KNBR];
#pragma unroll
    for (int k = 0; k < KNBR; ++k) uA[k] = g3h[(size_t)idsA[k]];
#pragma unroll
    for (int k = 0; k < KNBR; ++k) uB[k] = g3h[(size_t)idsB[k]];

    float a0=0.f, a1=0.f, a2=0.f, b0=0.f, b1=0.f, b2=0.f;
#pragma unroll
    for (int k = 0; k < KNBR; ++k) {
        float f0,f1,f2;
        unpack3(uA[k], f0,f1,f2);
        a0 += f0*wwsA[k]; a1 += f1*wwsA[k]; a2 += f2*wwsA[k];
    }
#pragma unroll
    for (int k = 0; k < KNBR; ++k) {
        float f0,f1,f2;
        unpack3(uB[k], f0,f1,f2);
        b0 += f0*wwsB[k]; b1 += f1*wwsB[k]; b2 += f2*wwsB[k];
    }
    float* opA = out + (size_t)n1*3;
    float* opB = out + (size_t)n2*3;
    __builtin_nontemporal_store(a0, opA+0);
    __builtin_nontemporal_store(a1, opA+1);
    __builtin_nontemporal_store(a2, opA+2);
    __builtin_nontemporal_store(b0, opB+0);
    __builtin_nontemporal_store(b1, opB+1);
    __builtin_nontemporal_store(b2, opB+2);
}

// ---------------------------------------------------------------------------
extern "C" void kernel_launch(void* const* d_in, const int* in_sizes, int n_in,
                              void* d_out, int out_size, void* d_ws, size_t ws_size,
                              hipStream_t stream) {
    const float* x    = (const float*)d_in[0];
    const float* y    = (const float*)d_in[1];
    const float* z    = (const float*)d_in[2];
    const float* wt   = (const float*)d_in[3];
    const int*   bidx = (const int*)d_in[4];
    const float* bw   = (const float*)d_in[5];
    float* out = (float*)d_out;
    float* ws  = (float*)d_ws;

    float* t1  = ws + T1_OFF;
    float* tvp = ws + TVP_OFF;
    uint2* g3h = (uint2*)(ws + G3_OFF);
    int np = in_sizes[4] / KNBR;   // 2,000,000

    k1  <<<dim3(12, 10, 3), 256, 0, stream>>>(x, wt, t1);
    kbcd<<<dim3(2, NX),     192, 0, stream>>>(y, z, t1, g3h);

    ktv <<<dim3(NBTV), 256, 0, stream>>>(g3h, tvp);
    kred<<<dim3(1),    256, 0, stream>>>(tvp, out + (out_size - 1));

    kgather<<<dim3((np/2 + 255) / 256), 256, 0, stream>>>(bidx, bw, g3h, out, np);
}